// Round 8
// baseline (1009.750 us; speedup 1.0000x reference)
//
#include <hip/hip_runtime.h>

#define N_TOK    32768
#define NEMBED   1024
#define SCALE    32.0f   // sqrt(1024)
#define NTHREADS 256     // 4 waves per block

// static grid partition (4 blocks/CU, 1024 blocks)
#define G0 32
#define G1 320    // %4==0  : bucket1, cs x4 (256-col slices)
#define G2 544    // %8==0  : bucket2, cs x8 (128-col slices)
#define G3 128    // %8==0  : bucket3, cs x8
#define GRID (G0 + G1 + G2 + G3)   // 1024

__device__ __forceinline__ int bucket_of(int idx) {
    return (idx < 20000) ? 0 : (idx < 40000) ? 1 : (idx < 200000) ? 2 : 3;
}

// ---------------- classify + compact tokens into per-bucket lists ----------------
__global__ void classify_kernel(const int* __restrict__ x,
                                int* __restrict__ cnt,      // [4]
                                int* __restrict__ lists) {  // [4][N_TOK]
    __shared__ int s_cnt[4], s_base[4];
    int tid = threadIdx.x;
    if (tid < 4) s_cnt[tid] = 0;
    __syncthreads();
    int t = blockIdx.x * blockDim.x + tid;
    int b = 0, p = 0;
    if (t < N_TOK) {
        b = bucket_of(x[t]);
        p = atomicAdd(&s_cnt[b], 1);
    }
    __syncthreads();
    if (tid < 4) s_base[tid] = atomicAdd(&cnt[tid], s_cnt[tid]);
    __syncthreads();
    if (t < N_TOK) lists[b * N_TOK + s_base[b] + p] = t;
}

// ---------------- bucket 0: per-wave row copy (no LDS, no barriers) ----------------
__device__ __forceinline__ void run_copy(const int* __restrict__ x,
                                         const float* __restrict__ table0,
                                         const int* __restrict__ list0,
                                         float* __restrict__ out,
                                         int n, int wv, int nw) {
    if (n <= 0 || wv >= n) return;
    int lane = threadIdx.x & 63;
    const float4* t4 = (const float4*)table0;
    float4* o4 = (float4*)out;
    int i = wv;
    int tok = list0[i];
    int row = x[tok];
    #pragma unroll 1
    while (i < n) {
        int ni = i + nw;
        int ntok = (ni < n) ? list0[ni] : -1;       // prefetch next id
        #pragma unroll
        for (int q = 0; q < 4; ++q) {
            float4 v = t4[(size_t)row * 256 + q * 64 + lane];
            v.x *= SCALE; v.y *= SCALE; v.z *= SCALE; v.w *= SCALE;
            o4[(size_t)tok * 256 + q * 64 + lane] = v;
        }
        int nrow = (ntok >= 0) ? x[ntok] : -1;
        i = ni; tok = ntok; row = nrow;
    }
}

// ---------------- buckets 2/3: P slice (f2 cols) in LDS once; per-wave token chunks ----
// cs in [0,8): cols [cs*128, cs*128+128). Lane owns 2 cols. Wave chunk = 8 tokens.
// E rows read from global with wave-uniform addresses (single 16B txn, L1-hot).
template <int D>
__device__ __forceinline__ void run_proj_small(const int* __restrict__ x,
                                               const float* __restrict__ table,
                                               const float* __restrict__ proj,
                                               const int* __restrict__ list_b,
                                               float* __restrict__ out,
                                               int n, int start, int cs,
                                               int wv0, int nwv,
                                               float4* __restrict__ PL) {
    constexpr int D4 = D / 4, D2 = D / 2;
    int tid = threadIdx.x, lane = tid & 63;

    // one-time: stage P slice. PL[k2*64+l] = (P[2k2][cA],P[2k2][cB],P[2k2+1][cA],P[2k2+1][cB])
    #pragma unroll 1
    for (int idx = tid; idx < D2 * 64; idx += NTHREADS) {
        int k2 = idx >> 6, l = idx & 63;
        int c = cs * 128 + 2 * l;
        const float* r0 = &proj[(size_t)(2 * k2) * NEMBED + c];
        const float* r1 = &proj[(size_t)(2 * k2 + 1) * NEMBED + c];
        PL[idx] = make_float4(r0[0], r0[1], r1[0], r1[1]);
    }
    __syncthreads();
    if (n <= 0 || wv0 >= ((n + 7) >> 3)) return;

    int nch = (n + 7) >> 3;
    const float4* tb4 = (const float4*)table;

    int toks[8], rows[8];
    #pragma unroll
    for (int j = 0; j < 8; ++j) {
        int i = wv0 * 8 + j;
        toks[j] = (i < n) ? list_b[i] : -1;
    }
    #pragma unroll
    for (int j = 0; j < 8; ++j)
        rows[j] = (toks[j] >= 0) ? (x[toks[j]] - start) : -1;

    #pragma unroll 1
    for (int c = wv0; c < nch; ) {
        int nc = c + nwv;
        int ntoks[8];
        #pragma unroll
        for (int j = 0; j < 8; ++j) {                // prefetch next chunk ids
            int i = nc * 8 + j;
            ntoks[j] = (nc < nch && i < n) ? list_b[i] : -1;
        }

        float2 acc[8];
        #pragma unroll
        for (int j = 0; j < 8; ++j) acc[j] = make_float2(0.f, 0.f);

        #pragma unroll 1
        for (int kg = 0; kg < D4; ++kg) {
            float4 e[8];
            #pragma unroll
            for (int j = 0; j < 8; ++j)
                e[j] = (rows[j] >= 0) ? tb4[(size_t)rows[j] * D4 + kg]
                                      : make_float4(0.f, 0.f, 0.f, 0.f);
            float4 p1 = PL[(2 * kg) * 64 + lane];
            float4 p2 = PL[(2 * kg + 1) * 64 + lane];
            #pragma unroll
            for (int j = 0; j < 8; ++j) {
                acc[j].x += e[j].x * p1.x + e[j].y * p1.z + e[j].z * p2.x + e[j].w * p2.z;
                acc[j].y += e[j].x * p1.y + e[j].y * p1.w + e[j].z * p2.y + e[j].w * p2.w;
            }
        }

        int nrows[8];
        #pragma unroll
        for (int j = 0; j < 8; ++j)                  // resolve next rows (covers store time)
            nrows[j] = (ntoks[j] >= 0) ? (x[ntoks[j]] - start) : -1;

        #pragma unroll
        for (int j = 0; j < 8; ++j) {
            if (toks[j] >= 0) {
                float2 v = make_float2(acc[j].x * SCALE, acc[j].y * SCALE);
                *(float2*)&out[(size_t)toks[j] * NEMBED + cs * 128 + 2 * lane] = v;
            }
        }
        c = nc;
        #pragma unroll
        for (int j = 0; j < 8; ++j) { toks[j] = ntoks[j]; rows[j] = nrows[j]; }
    }
}

// ---------------- bucket 1: D=256; P streamed through LDS in 16-row pieces (dbuf) ----
// cs in [0,4): cols [cs*256, +256), lane owns float4. Block chunk = 32 tokens (4 waves x 8).
__device__ __forceinline__ void run_proj_big(const int* __restrict__ x,
                                             const float* __restrict__ table,
                                             const float* __restrict__ proj,
                                             const int* __restrict__ list_b,
                                             float* __restrict__ out,
                                             int n, int start, int cs,
                                             int ch0, int chstride,
                                             float4* __restrict__ PL) {  // 2 x 1024 f4
    constexpr int D4 = 64;     // E f4s per row
    constexpr int NP = 16;     // pieces (16 rows each)
    int tid = threadIdx.x, lane = tid & 63, tg = tid >> 6;
    int nch = (n + 31) >> 5;
    const float4* tb4 = (const float4*)table;
    const float4* pj4 = (const float4*)proj;

    #pragma unroll 1
    for (int c = ch0; c < nch; c += chstride) {
        // ids for this wave's 8 tokens (wave-uniform loads)
        int toks[8], rows[8];
        #pragma unroll
        for (int j = 0; j < 8; ++j) {
            int i = c * 32 + tg * 8 + j;
            toks[j] = (i < n) ? list_b[i] : -1;
        }
        #pragma unroll
        for (int j = 0; j < 8; ++j)
            rows[j] = (toks[j] >= 0) ? (x[toks[j]] - start) : -1;

        float4 acc[8];
        #pragma unroll
        for (int j = 0; j < 8; ++j) acc[j] = make_float4(0.f, 0.f, 0.f, 0.f);

        // prologue: stage piece 0
        float4 sreg[4];
        #pragma unroll
        for (int q = 0; q < 4; ++q) {
            int idx = tid * 4 + q;                       // [0,1024)
            int r = idx >> 6, c4 = idx & 63;
            sreg[q] = pj4[(size_t)r * 256 + cs * 64 + c4];
        }
        #pragma unroll
        for (int q = 0; q < 4; ++q) PL[tid * 4 + q] = sreg[q];
        __syncthreads();

        #pragma unroll 1
        for (int p = 0; p < NP; ++p) {
            int buf = p & 1;
            // issue next piece loads early (hidden under compute)
            if (p + 1 < NP) {
                #pragma unroll
                for (int q = 0; q < 4; ++q) {
                    int idx = tid * 4 + q;
                    int r = (p + 1) * 16 + (idx >> 6), c4 = idx & 63;
                    sreg[q] = pj4[(size_t)r * 256 + cs * 64 + c4];
                }
            }
            const float4* B = PL + buf * 1024;
            #pragma unroll
            for (int kgl = 0; kgl < 4; ++kgl) {
                float4 e[8];
                #pragma unroll
                for (int j = 0; j < 8; ++j)
                    e[j] = (rows[j] >= 0) ? tb4[(size_t)rows[j] * D4 + p * 4 + kgl]
                                          : make_float4(0.f, 0.f, 0.f, 0.f);
                float4 q0 = B[(4 * kgl + 0) * 64 + lane];
                float4 q1 = B[(4 * kgl + 1) * 64 + lane];
                float4 q2 = B[(4 * kgl + 2) * 64 + lane];
                float4 q3 = B[(4 * kgl + 3) * 64 + lane];
                #pragma unroll
                for (int j = 0; j < 8; ++j) {
                    float4 ev = e[j];
                    acc[j].x += ev.x * q0.x + ev.y * q1.x + ev.z * q2.x + ev.w * q3.x;
                    acc[j].y += ev.x * q0.y + ev.y * q1.y + ev.z * q2.y + ev.w * q3.y;
                    acc[j].z += ev.x * q0.z + ev.y * q1.z + ev.z * q2.z + ev.w * q3.z;
                    acc[j].w += ev.x * q0.w + ev.y * q1.w + ev.z * q2.w + ev.w * q3.w;
                }
            }
            // commit next piece to the other buffer, then sync
            if (p + 1 < NP) {
                float4* W = PL + (buf ^ 1) * 1024;
                #pragma unroll
                for (int q = 0; q < 4; ++q) W[tid * 4 + q] = sreg[q];
            }
            __syncthreads();
        }

        #pragma unroll
        for (int j = 0; j < 8; ++j) {
            if (toks[j] >= 0) {
                float4 v = acc[j];
                v.x *= SCALE; v.y *= SCALE; v.z *= SCALE; v.w *= SCALE;
                *(float4*)&out[(size_t)toks[j] * NEMBED + cs * 256 + lane * 4] = v;
            }
        }
    }
}

// ---------------- fused kernel: static block partition ----------------
__global__ __launch_bounds__(NTHREADS, 4)
void fused_embed_kernel(const int* __restrict__ x,
                        const float* __restrict__ t0, const float* __restrict__ t1,
                        const float* __restrict__ t2, const float* __restrict__ t3,
                        const float* __restrict__ p1, const float* __restrict__ p2,
                        const float* __restrict__ p3,
                        const int* __restrict__ cnt,
                        const int* __restrict__ lists,
                        float* __restrict__ out) {
    __shared__ __align__(16) float4 PL[2048];   // 32 KB
    int bid = blockIdx.x;
    int tg = threadIdx.x >> 6;

    if (bid < G0) {
        run_copy(x, t0, lists, out, cnt[0], bid * 4 + tg, G0 * 4);
    } else if (bid < G0 + G1) {
        int lb = bid - G0;
        run_proj_big(x, t1, p1, lists + 1 * N_TOK, out, cnt[1], 20000,
                     lb & 3, lb >> 2, G1 / 4, PL);
    } else if (bid < G0 + G1 + G2) {
        int lb = bid - (G0 + G1);
        run_proj_small<64>(x, t2, p2, lists + 2 * N_TOK, out, cnt[2], 40000,
                           lb & 7, (lb >> 3) * 4 + tg, (G2 / 8) * 4, PL);
    } else {
        int lb = bid - (G0 + G1 + G2);
        run_proj_small<16>(x, t3, p3, lists + 3 * N_TOK, out, cnt[3], 200000,
                           lb & 7, (lb >> 3) * 4 + tg, (G3 / 8) * 4, PL);
    }
}

extern "C" void kernel_launch(void* const* d_in, const int* in_sizes, int n_in,
                              void* d_out, int out_size, void* d_ws, size_t ws_size,
                              hipStream_t stream) {
    const int*   x  = (const int*)d_in[0];
    const float* t0 = (const float*)d_in[1];
    const float* t1 = (const float*)d_in[2];
    const float* t2 = (const float*)d_in[3];
    const float* t3 = (const float*)d_in[4];
    const float* p1 = (const float*)d_in[5];
    const float* p2 = (const float*)d_in[6];
    const float* p3 = (const float*)d_in[7];
    float* out = (float*)d_out;

    int* cnt   = (int*)d_ws;
    int* lists = cnt + 64;

    hipMemsetAsync(d_ws, 0, 64 * sizeof(int), stream);
    classify_kernel<<<N_TOK / 256, 256, 0, stream>>>(x, cnt, lists);

    fused_embed_kernel<<<GRID, NTHREADS, 0, stream>>>(x, t0, t1, t2, t3, p1, p2, p3,
                                                      cnt, lists, out);
}

// Round 9
// 119.893 us; speedup vs baseline: 8.4221x; 8.4221x over previous
//
#include <hip/hip_runtime.h>

#define N_TOK    32768
#define NEMBED   1024
#define SCALE    32.0f   // sqrt(1024)
#define NTHREADS 512     // 8 waves per block

// persistent grid: 512 blocks = 2 blocks/CU, one generation.
// partition balanced by per-block FMA cycles (chunk = 4.19 MFLOP for all buckets):
//   b1: 1.29GF -> 136 blocks, b2: 2.57GF -> 288, b3: 0.27GF + write-heavy -> 56, b0 copy -> 32
#define G0 32
#define G1 136    // %4==0 (cs slices)
#define G2 288    // %4==0
#define G3 56     // %4==0
#define GRID (G0 + G1 + G2 + G3)   // 512

__device__ __forceinline__ int bucket_of(int idx) {
    return (idx < 20000) ? 0 : (idx < 40000) ? 1 : (idx < 200000) ? 2 : 3;
}

// ---------------- classify + compact tokens into per-bucket lists ----------------
__global__ void classify_kernel(const int* __restrict__ x,
                                int* __restrict__ cnt,      // [4]
                                int* __restrict__ lists) {  // [4][N_TOK]
    __shared__ int s_cnt[4], s_base[4];
    int tid = threadIdx.x;
    if (tid < 4) s_cnt[tid] = 0;
    __syncthreads();
    int t = blockIdx.x * blockDim.x + tid;
    int b = 0, p = 0;
    if (t < N_TOK) {
        b = bucket_of(x[t]);
        p = atomicAdd(&s_cnt[b], 1);
    }
    __syncthreads();
    if (tid < 4) s_base[tid] = atomicAdd(&cnt[tid], s_cnt[tid]);
    __syncthreads();
    if (t < N_TOK) lists[b * N_TOK + s_base[b] + p] = t;
}

// ---------------- bucket 0: row copy, chunks of 32 tokens ----------------
__device__ __forceinline__ void run_copy(const int* __restrict__ x,
                                         const float* __restrict__ table0,
                                         const int* __restrict__ list0,
                                         float* __restrict__ out,
                                         int n, int tile0, int stride,
                                         int* s_tok, int* s_row) {
    int ntiles = (n + 31) / 32;
    int tid = threadIdx.x;
    const float4* t4 = (const float4*)table0;
    float4* o4 = (float4*)out;
    #pragma unroll 1
    for (int t = tile0; t < ntiles; t += stride) {
        if (tid < 32) {
            int i = t * 32 + tid;
            int tok = (i < n) ? list0[i] : -1;
            s_tok[tid] = tok;
            s_row[tid] = (tok >= 0) ? x[tok] : -1;
        }
        __syncthreads();
        #pragma unroll 1
        for (int q = 0; q < 16; ++q) {
            int f4 = q * NTHREADS + tid;          // 0..8191 = 32 tok x 256 f4
            int tt = f4 >> 8, c4 = f4 & 255;
            int tok = s_tok[tt];
            if (tok >= 0) {
                float4 v = t4[(size_t)s_row[tt] * 256 + c4];
                v.x *= SCALE; v.y *= SCALE; v.z *= SCALE; v.w *= SCALE;
                o4[(size_t)tok * 256 + c4] = v;
            }
        }
        __syncthreads();
    }
}

// ---------------- buckets 2/3: proj slice in LDS, fixed cs per block ----------------
// chunk = 32 tokens; 8 waves x 4 tokens; lane owns float4 of cols [cs*256 .. +256)
template <int D>
__device__ __forceinline__ void run_proj_lds(const int* __restrict__ x,
                                             const float* __restrict__ table,
                                             const float* __restrict__ proj,
                                             const int* __restrict__ list_b,
                                             float* __restrict__ out,
                                             int n, int start,
                                             int cs, int chunk0, int cstride,
                                             float* __restrict__ Pb,
                                             float* __restrict__ Eb,
                                             int* __restrict__ s_tok,
                                             int* __restrict__ s_row) {
    constexpr int D4   = D / 4;
    constexpr int NF4P = D * 64;          // proj-slice float4s (D rows x 256 cols)
    constexpr int QP   = NF4P / NTHREADS; // 8 for D=64, 2 for D=16
    constexpr int NF4E = 32 * D4;         // E-tile float4s (512 for D=64, 128 for D=16)

    int tid = threadIdx.x;
    int nchunk = (n + 31) / 32;
    int myN = (chunk0 < nchunk) ? ((nchunk - 1 - chunk0) / cstride + 1) : 0;
    if (myN == 0) return;

    float4* P4 = (float4*)Pb;
    float4* E4 = (float4*)Eb;
    const float4* pj4 = (const float4*)proj;
    const float4* tb4 = (const float4*)table;

    // one-time: stage proj slice [D][256] into LDS (coalesced)
    #pragma unroll
    for (int q = 0; q < QP; ++q) {
        int f4 = q * NTHREADS + tid;
        int r = f4 >> 6, c4 = f4 & 63;
        P4[f4] = pj4[(size_t)r * 256 + cs * 64 + c4];
    }
    // ids(0), ids(1)
    if (tid < 32) {
        int i = chunk0 * 32 + tid;
        int tok = (i < n) ? list_b[i] : -1;
        s_tok[tid] = tok;
        s_row[tid] = (tok >= 0) ? (x[tok] - start) : -1;
        if (myN > 1) {
            int i1 = (chunk0 + cstride) * 32 + tid;
            int tok1 = (i1 < n) ? list_b[i1] : -1;
            s_tok[32 + tid] = tok1;
            s_row[32 + tid] = (tok1 >= 0) ? (x[tok1] - start) : -1;
        }
    }
    __syncthreads();
    // E(0)
    if (tid < NF4E) {
        int row = s_row[tid / D4];
        E4[tid] = (row >= 0) ? tb4[(size_t)row * D4 + (tid % D4)]
                             : make_float4(0.f, 0.f, 0.f, 0.f);
    }
    __syncthreads();

    int w = tid >> 6, lane = tid & 63;
    int col = cs * 256 + lane * 4;

    #pragma unroll 1
    for (int ti = 0; ti < myN; ++ti) {
        int sl = ti & 1;
        bool hn = (ti + 1 < myN), h2 = (ti + 2 < myN);

        // issue E(ti+1) gather -> reg (uses ids slot sl^1); overlaps compute
        float4 ereg = make_float4(0.f, 0.f, 0.f, 0.f);
        if (hn && tid < NF4E) {
            int row = s_row[(sl ^ 1) * 32 + tid / D4];
            if (row >= 0) ereg = tb4[(size_t)row * D4 + (tid % D4)];
        }
        // issue list(ti+2)
        int lreg = -1;
        if (h2 && tid < 32) {
            int i2 = (chunk0 + (ti + 2) * cstride) * 32 + tid;
            lreg = (i2 < n) ? list_b[i2] : -1;
        }

        // compute chunk ti: pure LDS + FMA
        float4 acc[4];
        #pragma unroll
        for (int j = 0; j < 4; j++) acc[j] = make_float4(0.f, 0.f, 0.f, 0.f);
        #pragma unroll 2
        for (int kg = 0; kg < D4; ++kg) {
            float4 p0 = P4[(4 * kg + 0) * 64 + lane];
            float4 p1 = P4[(4 * kg + 1) * 64 + lane];
            float4 p2 = P4[(4 * kg + 2) * 64 + lane];
            float4 p3 = P4[(4 * kg + 3) * 64 + lane];
            #pragma unroll
            for (int j = 0; j < 4; j++) {
                float4 e = E4[sl * NF4E + (4 * w + j) * D4 + kg];   // wave-uniform broadcast
                acc[j].x += e.x * p0.x + e.y * p1.x + e.z * p2.x + e.w * p3.x;
                acc[j].y += e.x * p0.y + e.y * p1.y + e.z * p2.y + e.w * p3.y;
                acc[j].z += e.x * p0.z + e.y * p1.z + e.z * p2.z + e.w * p3.z;
                acc[j].w += e.x * p0.w + e.y * p1.w + e.z * p2.w + e.w * p3.w;
            }
        }
        #pragma unroll
        for (int j = 0; j < 4; j++) {
            int tok = s_tok[sl * 32 + 4 * w + j];
            if (tok >= 0) {
                float4 v = acc[j];
                v.x *= SCALE; v.y *= SCALE; v.z *= SCALE; v.w *= SCALE;
                *(float4*)&out[(size_t)tok * NEMBED + col] = v;
            }
        }
        // resolve ids(ti+2)
        int row2 = -1;
        if (h2 && tid < 32 && lreg >= 0) row2 = x[lreg] - start;
        __syncthreads();
        if (hn && tid < NF4E) E4[(sl ^ 1) * NF4E + tid] = ereg;
        if (h2 && tid < 32) { s_tok[sl * 32 + tid] = lreg; s_row[sl * 32 + tid] = row2; }
        __syncthreads();
    }
}

// ---------------- bucket 1: D=256, proj from global (L2), col-split x4 by tile ----------------
// chunk = 16 tokens; tile = (chunk, cs); 8 waves x 2 tokens; lane owns float4 of cols
__device__ __forceinline__ void run_proj_g(const int* __restrict__ x,
                                           const float* __restrict__ table,
                                           const float* __restrict__ proj,
                                           const int* __restrict__ list_b,
                                           float* __restrict__ out,
                                           int n, int start,
                                           int tile0, int stride,
                                           float* __restrict__ Eb,
                                           int* __restrict__ s_tok,
                                           int* __restrict__ s_row) {
    constexpr int D4 = 64;
    int tid = threadIdx.x;
    int nchunk = (n + 15) / 16;
    int ntiles = nchunk * 4;
    int myN = (tile0 < ntiles) ? ((ntiles - 1 - tile0) / stride + 1) : 0;
    if (myN == 0) return;

    float4* E4 = (float4*)Eb;
    const float4* tb4 = (const float4*)table;

    if (tid < 16) {
        int i = (tile0 >> 2) * 16 + tid;
        int tok = (i < n) ? list_b[i] : -1;
        s_tok[tid] = tok;
        s_row[tid] = (tok >= 0) ? (x[tok] - start) : -1;
        if (myN > 1) {
            int i1 = ((tile0 + stride) >> 2) * 16 + tid;
            int tok1 = (i1 < n) ? list_b[i1] : -1;
            s_tok[32 + tid] = tok1;
            s_row[32 + tid] = (tok1 >= 0) ? (x[tok1] - start) : -1;
        }
    }
    __syncthreads();
    #pragma unroll
    for (int q = 0; q < 2; ++q) {                 // 1024 f4 = 16 tok x 64
        int f4 = tid * 2 + q;
        int row = s_row[f4 >> 6];
        E4[f4] = (row >= 0) ? tb4[(size_t)row * D4 + (f4 & 63)]
                            : make_float4(0.f, 0.f, 0.f, 0.f);
    }
    __syncthreads();

    int w = tid >> 6, lane = tid & 63;

    #pragma unroll 1
    for (int ti = 0; ti < myN; ++ti) {
        int sl = ti & 1;
        int tile = tile0 + ti * stride;
        int cs = tile & 3;
        bool hn = (ti + 1 < myN), h2 = (ti + 2 < myN);

        float4 er0 = make_float4(0.f, 0.f, 0.f, 0.f), er1 = er0;
        if (hn) {
            int f4a = tid * 2, f4b = tid * 2 + 1;
            int ra = s_row[(sl ^ 1) * 32 + (f4a >> 6)];
            int rb = s_row[(sl ^ 1) * 32 + (f4b >> 6)];
            if (ra >= 0) er0 = tb4[(size_t)ra * D4 + (f4a & 63)];
            if (rb >= 0) er1 = tb4[(size_t)rb * D4 + (f4b & 63)];
        }
        int lreg = -1;
        if (h2 && tid < 16) {
            int i2 = ((tile0 + (ti + 2) * stride) >> 2) * 16 + tid;
            lreg = (i2 < n) ? list_b[i2] : -1;
        }

        int col = cs * 256 + lane * 4;
        float4 acc0 = make_float4(0.f, 0.f, 0.f, 0.f), acc1 = acc0;
        #pragma unroll 2
        for (int kg = 0; kg < D4; ++kg) {
            float4 p0 = *(const float4*)&proj[(size_t)(4 * kg + 0) * NEMBED + col];
            float4 p1 = *(const float4*)&proj[(size_t)(4 * kg + 1) * NEMBED + col];
            float4 p2 = *(const float4*)&proj[(size_t)(4 * kg + 2) * NEMBED + col];
            float4 p3 = *(const float4*)&proj[(size_t)(4 * kg + 3) * NEMBED + col];
            float4 e0 = E4[sl * 1024 + (2 * w + 0) * D4 + kg];
            float4 e1 = E4[sl * 1024 + (2 * w + 1) * D4 + kg];
            acc0.x += e0.x * p0.x + e0.y * p1.x + e0.z * p2.x + e0.w * p3.x;
            acc0.y += e0.x * p0.y + e0.y * p1.y + e0.z * p2.y + e0.w * p3.y;
            acc0.z += e0.x * p0.z + e0.y * p1.z + e0.z * p2.z + e0.w * p3.z;
            acc0.w += e0.x * p0.w + e0.y * p1.w + e0.z * p2.w + e0.w * p3.w;
            acc1.x += e1.x * p0.x + e1.y * p1.x + e1.z * p2.x + e1.w * p3.x;
            acc1.y += e1.x * p0.y + e1.y * p1.y + e1.z * p2.y + e1.w * p3.y;
            acc1.z += e1.x * p0.z + e1.y * p1.z + e1.z * p2.z + e1.w * p3.z;
            acc1.w += e1.x * p0.w + e1.y * p1.w + e1.z * p2.w + e1.w * p3.w;
        }
        int tokA = s_tok[sl * 32 + 2 * w], tokB = s_tok[sl * 32 + 2 * w + 1];
        if (tokA >= 0) {
            float4 v = acc0;
            v.x *= SCALE; v.y *= SCALE; v.z *= SCALE; v.w *= SCALE;
            *(float4*)&out[(size_t)tokA * NEMBED + col] = v;
        }
        if (tokB >= 0) {
            float4 v = acc1;
            v.x *= SCALE; v.y *= SCALE; v.z *= SCALE; v.w *= SCALE;
            *(float4*)&out[(size_t)tokB * NEMBED + col] = v;
        }
        int row2 = -1;
        if (h2 && tid < 16 && lreg >= 0) row2 = x[lreg] - start;
        __syncthreads();
        if (hn) { E4[(sl ^ 1) * 1024 + tid * 2] = er0; E4[(sl ^ 1) * 1024 + tid * 2 + 1] = er1; }
        if (h2 && tid < 16) { s_tok[sl * 32 + tid] = lreg; s_row[sl * 32 + tid] = row2; }
        __syncthreads();
    }
}

// ---------------- fused kernel ----------------
__global__ __launch_bounds__(NTHREADS, 4)
void fused_embed_kernel(const int* __restrict__ x,
                        const float* __restrict__ t0, const float* __restrict__ t1,
                        const float* __restrict__ t2, const float* __restrict__ t3,
                        const float* __restrict__ p1, const float* __restrict__ p2,
                        const float* __restrict__ p3,
                        const int* __restrict__ cnt,
                        const int* __restrict__ lists,
                        float* __restrict__ out) {
    // 80 KB shared region (2 blocks/CU):
    //  b1: E dbuf (32 KB) at smem
    //  b2: P (64 KB) at smem, E dbuf (16 KB) at smem+16384
    //  b3: P (16 KB) at smem, E dbuf (4 KB) at smem+4096
    __shared__ __align__(16) float smem[20480];
    __shared__ int s_tok[64], s_row[64];

    int bid = blockIdx.x;
    if (bid < G0) {
        run_copy(x, t0, lists, out, cnt[0], bid, G0, s_tok, s_row);
    } else if (bid < G0 + G1) {
        run_proj_g(x, t1, p1, lists + 1 * N_TOK, out, cnt[1], 20000,
                   bid - G0, G1, smem, s_tok, s_row);
    } else if (bid < G0 + G1 + G2) {
        int lb = bid - (G0 + G1);
        run_proj_lds<64>(x, t2, p2, lists + 2 * N_TOK, out, cnt[2], 40000,
                         lb & 3, lb >> 2, G2 / 4, smem, smem + 16384, s_tok, s_row);
    } else {
        int lb = bid - (G0 + G1 + G2);
        run_proj_lds<16>(x, t3, p3, lists + 3 * N_TOK, out, cnt[3], 200000,
                         lb & 3, lb >> 2, G3 / 4, smem, smem + 4096, s_tok, s_row);
    }
}

extern "C" void kernel_launch(void* const* d_in, const int* in_sizes, int n_in,
                              void* d_out, int out_size, void* d_ws, size_t ws_size,
                              hipStream_t stream) {
    const int*   x  = (const int*)d_in[0];
    const float* t0 = (const float*)d_in[1];
    const float* t1 = (const float*)d_in[2];
    const float* t2 = (const float*)d_in[3];
    const float* t3 = (const float*)d_in[4];
    const float* p1 = (const float*)d_in[5];
    const float* p2 = (const float*)d_in[6];
    const float* p3 = (const float*)d_in[7];
    float* out = (float*)d_out;

    int* cnt   = (int*)d_ws;
    int* lists = cnt + 64;

    hipMemsetAsync(d_ws, 0, 64 * sizeof(int), stream);
    classify_kernel<<<N_TOK / 256, 256, 0, stream>>>(x, cnt, lists);

    fused_embed_kernel<<<GRID, NTHREADS, 0, stream>>>(x, t0, t1, t2, t3, p1, p2, p3,
                                                      cnt, lists, out);
}

// Round 10
// 89.887 us; speedup vs baseline: 11.2335x; 1.3338x over previous
//
#include <hip/hip_runtime.h>

#define N_TOK    32768
#define NEMBED   1024
#define SCALE    32.0f   // sqrt(1024)
#define NTHREADS 512     // 8 waves per block

// persistent grid: 512 blocks = 2 blocks/CU (64 KB LDS each), one generation.
// partition by MAC share: b1 644M, b2 1288M, b3 135M MACs; b0 copy-BW.
#define G0 24
#define G1 152   // %4==0 (cs col-slices)
#define G2 296   // %4==0
#define G3 40    // %4==0
#define GRID (G0 + G1 + G2 + G3)   // 512

__device__ __forceinline__ int bucket_of(int idx) {
    return (idx < 20000) ? 0 : (idx < 40000) ? 1 : (idx < 200000) ? 2 : 3;
}
__device__ __forceinline__ int rfl(int v) { return __builtin_amdgcn_readfirstlane(v); }

// ---------------- classify + compact tokens into per-bucket lists ----------------
__global__ void classify_kernel(const int* __restrict__ x,
                                int* __restrict__ cnt,      // [4]
                                int* __restrict__ lists) {  // [4][N_TOK]
    __shared__ int s_cnt[4], s_base[4];
    int tid = threadIdx.x;
    if (tid < 4) s_cnt[tid] = 0;
    __syncthreads();
    int t = blockIdx.x * blockDim.x + tid;
    int b = 0, p = 0;
    if (t < N_TOK) {
        b = bucket_of(x[t]);
        p = atomicAdd(&s_cnt[b], 1);
    }
    __syncthreads();
    if (tid < 4) s_base[tid] = atomicAdd(&cnt[tid], s_cnt[tid]);
    __syncthreads();
    if (t < N_TOK) lists[b * N_TOK + s_base[b] + p] = t;
}

// ---------------- bucket 0: per-wave row copy (ids in SGPR, no LDS/barriers) ------
__device__ __forceinline__ void run_copy(const int* __restrict__ x,
                                         const float* __restrict__ table0,
                                         const int* __restrict__ list0,
                                         float* __restrict__ out,
                                         int n, int wv0, int nwv) {
    int lane = threadIdx.x & 63;
    const float4* t4 = (const float4*)table0;
    float4* o4 = (float4*)out;
    #pragma unroll 1
    for (int i = wv0; i < n; i += nwv) {
        int tok = rfl(list0[i]);
        int row = rfl(x[tok]);
        #pragma unroll
        for (int q = 0; q < 4; ++q) {
            float4 v = t4[(size_t)row * 256 + q * 64 + lane];
            v.x *= SCALE; v.y *= SCALE; v.z *= SCALE; v.w *= SCALE;
            o4[(size_t)tok * 256 + q * 64 + lane] = v;
        }
    }
}

// ------ buckets 2/3: P slice resident in LDS; E via wave-uniform (scalar) loads ----
// cs in [0,4): cols [cs*256, +256); lane owns 4 cols. Wave chunk = 8 tokens.
// LDS traffic = P reads only (4 x b128 / kg / wave) -> below FMA capacity.
template <int D>
__device__ __forceinline__ void run_proj_reg(const int* __restrict__ x,
                                             const float* __restrict__ table,
                                             const float* __restrict__ proj,
                                             const int* __restrict__ list_b,
                                             float* __restrict__ out,
                                             int n, int start,
                                             int cs, int wv0, int nwv,
                                             float4* __restrict__ PL) {
    constexpr int D4   = D / 4;
    constexpr int NF4P = D * 64;             // P slice f4 count (D rows x 64 f4-cols)
    constexpr int QP   = NF4P / NTHREADS;    // 8 for D=64, 2 for D=16
    int tid = threadIdx.x, lane = tid & 63;
    const float4* pj4 = (const float4*)proj;
    const float4* tb4 = (const float4*)table;

    // one-time cooperative P staging (coalesced), single barrier
    #pragma unroll
    for (int q = 0; q < QP; ++q) {
        int f4 = q * NTHREADS + tid;
        int r = f4 >> 6, c4 = f4 & 63;
        PL[f4] = pj4[(size_t)r * 256 + cs * 64 + c4];
    }
    __syncthreads();

    int nch = (n + 7) >> 3;
    #pragma unroll 1
    for (int c = wv0; c < nch; c += nwv) {
        int toks[8], rows[8];
        #pragma unroll
        for (int j = 0; j < 8; ++j) {
            int i = c * 8 + j;
            toks[j] = rfl((i < n) ? list_b[i] : -1);
        }
        #pragma unroll
        for (int j = 0; j < 8; ++j)
            rows[j] = (toks[j] >= 0) ? rfl(x[toks[j]] - start) : 0;

        float4 acc[8];
        #pragma unroll
        for (int j = 0; j < 8; ++j) acc[j] = make_float4(0.f, 0.f, 0.f, 0.f);

        #pragma unroll 2
        for (int kg = 0; kg < D4; ++kg) {
            float4 p0 = PL[(4 * kg + 0) * 64 + lane];
            float4 p1 = PL[(4 * kg + 1) * 64 + lane];
            float4 p2 = PL[(4 * kg + 2) * 64 + lane];
            float4 p3 = PL[(4 * kg + 3) * 64 + lane];
            #pragma unroll
            for (int j = 0; j < 8; ++j) {
                float4 e = tb4[(size_t)rows[j] * D4 + kg];   // wave-uniform -> scalar path
                acc[j].x += e.x * p0.x + e.y * p1.x + e.z * p2.x + e.w * p3.x;
                acc[j].y += e.x * p0.y + e.y * p1.y + e.z * p2.y + e.w * p3.y;
                acc[j].z += e.x * p0.z + e.y * p1.z + e.z * p2.z + e.w * p3.z;
                acc[j].w += e.x * p0.w + e.y * p1.w + e.z * p2.w + e.w * p3.w;
            }
        }

        #pragma unroll
        for (int j = 0; j < 8; ++j) {
            if (toks[j] >= 0) {
                float4 v = acc[j];
                v.x *= SCALE; v.y *= SCALE; v.z *= SCALE; v.w *= SCALE;
                *(float4*)&out[(size_t)toks[j] * NEMBED + cs * 256 + lane * 4] = v;
            }
        }
    }
}

// ------ bucket 1: D=256; P slice streamed through LDS in 16-row dbuf pieces -------
// cs in [0,4): cols [cs*256, +256). Block chunk = 64 tokens (8 waves x 8).
__device__ __forceinline__ void run_proj_stream(const int* __restrict__ x,
                                                const float* __restrict__ table,
                                                const float* __restrict__ proj,
                                                const int* __restrict__ list_b,
                                                float* __restrict__ out,
                                                int n, int start,
                                                int cs, int blk0, int nblk,
                                                float4* __restrict__ PL) {  // 2x1024 f4
    int tid = threadIdx.x, lane = tid & 63, w = tid >> 6;
    const float4* pj4 = (const float4*)proj;
    const float4* tb4 = (const float4*)table;
    int nch = (n + 63) >> 6;

    #pragma unroll 1
    for (int c = blk0; c < nch; c += nblk) {
        int toks[8], rows[8];
        #pragma unroll
        for (int j = 0; j < 8; ++j) {
            int i = c * 64 + w * 8 + j;
            toks[j] = rfl((i < n) ? list_b[i] : -1);
        }
        #pragma unroll
        for (int j = 0; j < 8; ++j)
            rows[j] = (toks[j] >= 0) ? rfl(x[toks[j]] - start) : 0;

        float4 acc[8];
        #pragma unroll
        for (int j = 0; j < 8; ++j) acc[j] = make_float4(0.f, 0.f, 0.f, 0.f);

        int i0 = tid * 2, i1 = tid * 2 + 1;
        // prologue: stage piece 0 -> buf 0
        float4 s0 = pj4[(size_t)(i0 >> 6) * 256 + cs * 64 + (i0 & 63)];
        float4 s1 = pj4[(size_t)(i1 >> 6) * 256 + cs * 64 + (i1 & 63)];
        PL[i0] = s0; PL[i1] = s1;
        __syncthreads();

        #pragma unroll 1
        for (int p = 0; p < 16; ++p) {
            const float4* cur = PL + (p & 1) * 1024;
            if (p < 15) {   // issue next-piece loads early (hidden under FMA)
                int base = (p + 1) * 16;
                s0 = pj4[(size_t)(base + (i0 >> 6)) * 256 + cs * 64 + (i0 & 63)];
                s1 = pj4[(size_t)(base + (i1 >> 6)) * 256 + cs * 64 + (i1 & 63)];
            }
            #pragma unroll 2
            for (int g = 0; g < 4; ++g) {
                float4 p0 = cur[(4 * g + 0) * 64 + lane];
                float4 p1 = cur[(4 * g + 1) * 64 + lane];
                float4 p2 = cur[(4 * g + 2) * 64 + lane];
                float4 p3 = cur[(4 * g + 3) * 64 + lane];
                #pragma unroll
                for (int j = 0; j < 8; ++j) {
                    float4 e = tb4[(size_t)rows[j] * 64 + p * 4 + g];  // wave-uniform
                    acc[j].x += e.x * p0.x + e.y * p1.x + e.z * p2.x + e.w * p3.x;
                    acc[j].y += e.x * p0.y + e.y * p1.y + e.z * p2.y + e.w * p3.y;
                    acc[j].z += e.x * p0.z + e.y * p1.z + e.z * p2.z + e.w * p3.z;
                    acc[j].w += e.x * p0.w + e.y * p1.w + e.z * p2.w + e.w * p3.w;
                }
            }
            if (p < 15) {   // commit next piece to the other buffer
                float4* nb = PL + ((p + 1) & 1) * 1024;
                nb[i0] = s0; nb[i1] = s1;
            }
            __syncthreads();
        }

        #pragma unroll
        for (int j = 0; j < 8; ++j) {
            if (toks[j] >= 0) {
                float4 v = acc[j];
                v.x *= SCALE; v.y *= SCALE; v.z *= SCALE; v.w *= SCALE;
                *(float4*)&out[(size_t)toks[j] * NEMBED + cs * 256 + lane * 4] = v;
            }
        }
    }
}

// ---------------- fused kernel: static block partition ----------------
__global__ __launch_bounds__(NTHREADS, 4)   // VGPR cap 128; 2 blocks/CU via 64KB LDS
void fused_embed_kernel(const int* __restrict__ x,
                        const float* __restrict__ t0, const float* __restrict__ t1,
                        const float* __restrict__ t2, const float* __restrict__ t3,
                        const float* __restrict__ p1, const float* __restrict__ p2,
                        const float* __restrict__ p3,
                        const int* __restrict__ cnt,
                        const int* __restrict__ lists,
                        float* __restrict__ out) {
    __shared__ __align__(16) float4 PL[4096];   // 64 KB
    int bid = blockIdx.x;
    int w = threadIdx.x >> 6;

    if (bid < G0) {
        run_copy(x, t0, lists, out, cnt[0], bid * 8 + w, G0 * 8);
    } else if (bid < G0 + G1) {
        int lb = bid - G0;
        run_proj_stream(x, t1, p1, lists + 1 * N_TOK, out, cnt[1], 20000,
                        lb & 3, lb >> 2, G1 / 4, PL);
    } else if (bid < G0 + G1 + G2) {
        int lb = bid - (G0 + G1);
        run_proj_reg<64>(x, t2, p2, lists + 2 * N_TOK, out, cnt[2], 40000,
                         lb & 3, (lb >> 2) * 8 + w, (G2 / 4) * 8, PL);
    } else {
        int lb = bid - (G0 + G1 + G2);
        run_proj_reg<16>(x, t3, p3, lists + 3 * N_TOK, out, cnt[3], 200000,
                         lb & 3, (lb >> 2) * 8 + w, (G3 / 4) * 8, PL);
    }
}

extern "C" void kernel_launch(void* const* d_in, const int* in_sizes, int n_in,
                              void* d_out, int out_size, void* d_ws, size_t ws_size,
                              hipStream_t stream) {
    const int*   x  = (const int*)d_in[0];
    const float* t0 = (const float*)d_in[1];
    const float* t1 = (const float*)d_in[2];
    const float* t2 = (const float*)d_in[3];
    const float* t3 = (const float*)d_in[4];
    const float* p1 = (const float*)d_in[5];
    const float* p2 = (const float*)d_in[6];
    const float* p3 = (const float*)d_in[7];
    float* out = (float*)d_out;

    int* cnt   = (int*)d_ws;
    int* lists = cnt + 64;

    hipMemsetAsync(d_ws, 0, 64 * sizeof(int), stream);
    classify_kernel<<<N_TOK / 256, 256, 0, stream>>>(x, cnt, lists);

    fused_embed_kernel<<<GRID, NTHREADS, 0, stream>>>(x, t0, t1, t2, t3, p1, p2, p3,
                                                      cnt, lists, out);
}